// Round 10
// baseline (233.096 us; speedup 1.0000x reference)
//
#include <hip/hip_runtime.h>

typedef unsigned short u16;
typedef unsigned int u32;
typedef __attribute__((ext_vector_type(4))) float f32x4;
typedef __attribute__((ext_vector_type(8))) __bf16 bf16x8;
typedef __attribute__((ext_vector_type(4))) _Float16 f16x4;
typedef __attribute__((ext_vector_type(4))) u16 u16x4;
typedef __attribute__((ext_vector_type(4))) u32 u32x4;
typedef __attribute__((ext_vector_type(2))) u32 u32x2;

#define D_ 1024
#define S_ 2048
#define B_ 4
#define H_ 16
#define HD_ 64
#define M_ 8192
#define QSCALE 0.18033688011112042591f /* 0.125 * log2(e) */

__device__ __forceinline__ u16 f2bf(float f) {
  u32 u = __float_as_uint(f);
  u += 0x7fffu + ((u >> 16) & 1u);
  return (u16)(u >> 16);
}

__device__ __forceinline__ float max3f(float a, float b, float c) {
  return fmaxf(fmaxf(a, b), c);  // clang fuses to v_max3_f32
}

// async 16B global->LDS DMA; LDS dest = wave-uniform base + lane*16 (linear!)
__device__ __forceinline__ void gload_lds16(const void* g, void* l) {
  __builtin_amdgcn_global_load_lds((const __attribute__((address_space(1))) void*)g,
                                   (__attribute__((address_space(3))) void*)l, 16, 0, 0);
}

// ---------------- cast x (fp32 -> bf16) ----------------
__global__ __launch_bounds__(256) void cast_x_kernel(const float* __restrict__ x,
                                                     u16* __restrict__ xb) {
  int i = (blockIdx.x * 256 + threadIdx.x) * 4;
  f32x4 v = *(const f32x4*)(x + i);
  u16x4 o = {f2bf(v[0]), f2bf(v[1]), f2bf(v[2]), f2bf(v[3])};
  *(u16x4*)(xb + i) = o;
}

// ---------------- transpose+cast weights: Wt[n][k] = bf16(W[k][n]) ----------------
__global__ __launch_bounds__(256) void wtrans_kernel(const float* __restrict__ Wq, const float* __restrict__ Wk,
                                                     const float* __restrict__ Wv, const float* __restrict__ Wo,
                                                     u16* __restrict__ Wqt, u16* __restrict__ Wkt,
                                                     u16* __restrict__ Wvt, u16* __restrict__ Wot) {
  __shared__ float lds[64][65];
  const float* W = blockIdx.z == 0 ? Wq : blockIdx.z == 1 ? Wk : blockIdx.z == 2 ? Wv : Wo;
  u16* Wt       = blockIdx.z == 0 ? Wqt : blockIdx.z == 1 ? Wkt : blockIdx.z == 2 ? Wvt : Wot;
  int k0 = blockIdx.x * 64, n0 = blockIdx.y * 64;
  int tr = threadIdx.x >> 6, tc = threadIdx.x & 63;
#pragma unroll
  for (int i = 0; i < 16; ++i)
    lds[tr + i * 4][tc] = W[(size_t)(k0 + tr + i * 4) * D_ + n0 + tc];
  __syncthreads();
#pragma unroll
  for (int i = 0; i < 16; ++i)
    Wt[(size_t)(n0 + tr + i * 4) * D_ + k0 + tc] = f2bf(lds[tc][tr + i * 4]);
}

// ---------------- shared 128x128 GEMM mainloop (global_load_lds staging, XOR swizzle) ----------------
__device__ __forceinline__ void gemm_main(const u16* __restrict__ A, const u16* __restrict__ Bt,
                                          u16* As, u16* Bs, int row0, int col0, f32x4 acc[4][4]) {
  const int tid = threadIdx.x;
  const int lane = tid & 63, wave = tid >> 6;
  const int wr = wave >> 1, wc = wave & 1;
  const int l15 = lane & 15, lg = lane >> 4;
  const int sr8 = lane >> 3;        // row within this wave's 8-row chunk (= r&7)
  const int scx = (lane & 7) ^ sr8; // pre-swizzled source k-chunk
#pragma unroll 1
  for (int k0 = 0; k0 < D_; k0 += 64) {
    // issue async stages: 4 wave-chunks of 8 rows for A and B each
#pragma unroll
    for (int it = 0; it < 4; ++it) {
      int rbase = (it * 4 + wave) * 8;
      int r = rbase + sr8;
      gload_lds16(A + (size_t)(row0 + r) * D_ + k0 + scx * 8, As + rbase * 64);
      gload_lds16(Bt + (size_t)(col0 + r) * D_ + k0 + scx * 8, Bs + rbase * 64);
    }
    __syncthreads();  // drains vmcnt -> DMA writes visible; syncs waves
#pragma unroll
    for (int kk = 0; kk < 64; kk += 32) {
      const int cb = kk >> 3;  // 0 or 4
      bf16x8 af[4], bf[4];
#pragma unroll
      for (int m = 0; m < 4; ++m) {
        int row = wr * 64 + m * 16 + l15;
        af[m] = *(const bf16x8*)(As + row * 64 + (((cb + lg) ^ (l15 & 7)) << 3));
      }
#pragma unroll
      for (int n = 0; n < 4; ++n) {
        int row = wc * 64 + n * 16 + l15;
        bf[n] = *(const bf16x8*)(Bs + row * 64 + (((cb + lg) ^ (l15 & 7)) << 3));
      }
#pragma unroll
      for (int m = 0; m < 4; ++m)
#pragma unroll
        for (int n = 0; n < 4; ++n)
          acc[m][n] = __builtin_amdgcn_mfma_f32_16x16x32_bf16(af[m], bf[n], acc[m][n], 0, 0, 0);
    }
    __syncthreads();  // readers done before next iteration's DMA writes
  }
}

// ---------------- QKV projection GEMM (1D grid, XCD-clustered swizzle) ----------------
__global__ __launch_bounds__(256) void qkv_gemm_kernel(const u16* __restrict__ xb,
                                                       const u16* __restrict__ Wqt, const u16* __restrict__ Wkt,
                                                       const u16* __restrict__ Wvt,
                                                       u16* __restrict__ Qb, u16* __restrict__ Kb,
                                                       _Float16* __restrict__ Vt) {
  __shared__ u16 As[128 * 64];
  __shared__ u16 Bs[128 * 64];
  int lin = blockIdx.x;
  int xcd = lin & 7, pos = lin >> 3;      // pos in [0,192)
  int mode = pos / 64;                    // z outer
  int rem = pos & 63;
  int by = xcd * 8 + (rem >> 3);          // row-panel
  int bx = rem & 7;                       // col-tile
  const u16* Bt = mode == 0 ? Wqt : mode == 1 ? Wkt : Wvt;
  f32x4 acc[4][4] = {};
  int row0 = by * 128, col0 = bx * 128;
  gemm_main(xb, Bt, As, Bs, row0, col0, acc);
  int lane = threadIdx.x & 63, wave = threadIdx.x >> 6;
  int wr = wave >> 1, wc = wave & 1, l15 = lane & 15, lg = lane >> 4;
  int rbase = row0 + wr * 64 + lg * 4, cbase = col0 + wc * 64 + l15;
  if (mode == 2) {
#pragma unroll
    for (int m = 0; m < 4; ++m) {
      int row = rbase + m * 16;
      int b = row >> 11, s = row & (S_ - 1);
#pragma unroll
      for (int n = 0; n < 4; ++n) {
        int col = cbase + n * 16;
        int h = col >> 6, hd = col & 63;
        f16x4 vv = {(_Float16)acc[m][n][0], (_Float16)acc[m][n][1],
                    (_Float16)acc[m][n][2], (_Float16)acc[m][n][3]};
        *(f16x4*)(Vt + ((size_t)((b << 4) + h) * HD_ + hd) * S_ + s) = vv;
      }
    }
  } else {
    u16* dst = mode == 0 ? Qb : Kb;
    float scl = mode == 0 ? QSCALE : 1.0f;
#pragma unroll
    for (int m = 0; m < 4; ++m)
#pragma unroll
      for (int n = 0; n < 4; ++n) {
        int col = cbase + n * 16;
#pragma unroll
        for (int r = 0; r < 4; ++r) {
          int row = rbase + m * 16 + r;
          dst[(size_t)row * D_ + col] = f2bf(acc[m][n][r] * scl);
        }
      }
  }
}

// ---------------- fused causal flash attention, v8: dual Q-fragment + DMA staging ----------------
// Block = 4 waves, one (b,h), handles BOTH paired q-blocks (qbA=31-p heavy, qbB=p light)
// in ONE kv sweep: every K/V LDS read is shared by two Q fragments -> LDS read bytes
// per unit compute nearly halve; staged tiles per block drop 33 -> 32-p.
// K/V staged via global_load_lds (linear dest, XOR-pre-swizzled source chunk c^(r&7),
// same XOR on fragment reads -> bank-uniform). LDS 32KB -> 4 blocks/CU.
__global__ __launch_bounds__(256) void attn_kernel(const u16* __restrict__ Qb, const u16* __restrict__ Kb,
                                                   const _Float16* __restrict__ Vt, u16* __restrict__ attnb) {
  __shared__ u16 Ks[2][64][64];       // [kv][hd], chunk-swizzled
  __shared__ _Float16 Vs[2][64][64];  // [hd][kv], chunk-swizzled
  const int tid = threadIdx.x;
  const int wave = tid >> 6, lane = tid & 63;
  const int l15 = lane & 15, lg = lane >> 4;
  const int lin = blockIdx.x;
  const int xcd = lin & 7, slot = lin >> 3;  // slot 0..127
  const int p = slot >> 3;                   // pair index 0..15
  const int bh = (slot & 7) * 8 + xcd;       // bh&7 == xcd
  const int b = bh >> 4, h = bh & 15;
  const int ntA = 32 - p, ntB = p + 1;       // tiles for heavy/light fragment
  const int q0A = (31 - p) * 64 + wave * 16;
  const int q0B = p * 64 + wave * 16;

  const u16* Kg = Kb + (size_t)(b * S_) * D_ + h * HD_;
  const _Float16* Vg = Vt + (size_t)bh * HD_ * S_;

  // DMA staging: lane covers row wr0+(lane>>3), phys chunk lane&7 <- source chunk (lane&7)^(row&7)
  const int srow = lane >> 3;
  const int scs = (lane & 7) ^ srow;
  const int wr0 = wave * 8;

  // Q fragments (global, L2-hot)
  const u16* QrowA = Qb + (size_t)(b * S_ + q0A + l15) * D_ + h * HD_;
  bf16x8 qA0 = *(const bf16x8*)(QrowA + lg * 8);
  bf16x8 qA1 = *(const bf16x8*)(QrowA + 32 + lg * 8);
  const u16* QrowB = Qb + (size_t)(b * S_ + q0B + l15) * D_ + h * HD_;
  bf16x8 qB0 = *(const bf16x8*)(QrowB + lg * 8);
  bf16x8 qB1 = *(const bf16x8*)(QrowB + 32 + lg * 8);

  float mA = -1e30f, mB = -1e30f;
  f32x4 oA[4] = {}, oB[4] = {};
  f32x4 osA = {}, osB = {};
  const f16x4 ones16 = {(_Float16)1.0f, (_Float16)1.0f, (_Float16)1.0f, (_Float16)1.0f};

  // fragment-read address pieces (swizzle XOR with row&7 = l15&7)
  const int rx = l15 & 7;
  const int kc0 = (lg ^ rx) << 3;   // kf0 chunk offset (u16 elems)
  const int kc1 = kc0 ^ 32;         // kf1 = chunk^4
  const int lgh = lg >> 1, lgb = (lg & 1) * 4;
  const int qrm = wave * 16 + l15;  // local row for diagonal mask

  // prologue: stage tile 0 into buf0
  gload_lds16(Kg + (size_t)(wr0 + srow) * D_ + scs * 8, &Ks[0][wr0][0]);
  gload_lds16(Kg + (size_t)(32 + wr0 + srow) * D_ + scs * 8, &Ks[0][32 + wr0][0]);
  gload_lds16(Vg + (size_t)(wr0 + srow) * S_ + scs * 8, &Vs[0][wr0][0]);
  gload_lds16(Vg + (size_t)(32 + wr0 + srow) * S_ + scs * 8, &Vs[0][32 + wr0][0]);

#pragma unroll 1
  for (int t = 0; t < ntA; ++t) {
    const int cur = t & 1;
    __syncthreads();  // drains DMA for tile t (vmcnt before barrier), syncs waves
    if (t + 1 < ntA) {
      const int kv0 = (t + 1) * 64;
      const int nxt = cur ^ 1;
      gload_lds16(Kg + (size_t)(kv0 + wr0 + srow) * D_ + scs * 8, &Ks[nxt][wr0][0]);
      gload_lds16(Kg + (size_t)(kv0 + 32 + wr0 + srow) * D_ + scs * 8, &Ks[nxt][32 + wr0][0]);
      gload_lds16(Vg + (size_t)(wr0 + srow) * S_ + kv0 + scs * 8, &Vs[nxt][wr0][0]);
      gload_lds16(Vg + (size_t)(32 + wr0 + srow) * S_ + kv0 + scs * 8, &Vs[nxt][32 + wr0][0]);
    }
    const bool actB = t < ntB;

    // ---- QK^T: K fragments read once, shared by both Q fragments ----
    f32x4 sA[4], sB[4];
    __builtin_amdgcn_s_setprio(1);
#pragma unroll
    for (int j = 0; j < 4; ++j) {
      const u16* krow = &Ks[cur][j * 16 + l15][0];
      bf16x8 kf0 = *(const bf16x8*)(krow + kc0);
      bf16x8 kf1 = *(const bf16x8*)(krow + kc1);
      f32x4 zA = {0.f, 0.f, 0.f, 0.f};
      zA = __builtin_amdgcn_mfma_f32_16x16x32_bf16(kf0, qA0, zA, 0, 0, 0);
      zA = __builtin_amdgcn_mfma_f32_16x16x32_bf16(kf1, qA1, zA, 0, 0, 0);
      sA[j] = zA;
      if (actB) {
        f32x4 zB = {0.f, 0.f, 0.f, 0.f};
        zB = __builtin_amdgcn_mfma_f32_16x16x32_bf16(kf0, qB0, zB, 0, 0, 0);
        zB = __builtin_amdgcn_mfma_f32_16x16x32_bf16(kf1, qB1, zB, 0, 0, 0);
        sB[j] = zB;
      }
    }
    __builtin_amdgcn_s_setprio(0);

    // ---- diagonal masks ----
    if (t == ntA - 1) {
#pragma unroll
      for (int j = 0; j < 4; ++j)
#pragma unroll
        for (int r = 0; r < 4; ++r)
          if (j * 16 + lg * 4 + r > qrm) sA[j][r] = -1e30f;
    }
    if (actB && t == ntB - 1) {
#pragma unroll
      for (int j = 0; j < 4; ++j)
#pragma unroll
        for (int r = 0; r < 4; ++r)
          if (j * 16 + lg * 4 + r > qrm) sB[j][r] = -1e30f;
    }

    // ---- online softmax helper ----
    auto softmax = [&](f32x4 s[4], float& mm, f32x4 oo[4], f32x4& osum, f16x4 pb[4]) {
      float x0 = max3f(s[0][0], s[0][1], s[0][2]);
      float x1 = max3f(s[0][3], s[1][0], s[1][1]);
      float x2 = max3f(s[1][2], s[1][3], s[2][0]);
      float x3 = max3f(s[2][1], s[2][2], s[2][3]);
      float x4 = max3f(s[3][0], s[3][1], s[3][2]);
      float tmax = fmaxf(max3f(x0, x1, x2), max3f(x3, x4, s[3][3]));
      tmax = fmaxf(tmax, __shfl_xor(tmax, 16));
      tmax = fmaxf(tmax, __shfl_xor(tmax, 32));
      if (!__all(tmax - mm <= 8.f)) {  // defer-max (T13)
        float nm = fmaxf(mm, tmax);
        float alpha = exp2f(mm - nm);
        mm = nm;
        osum *= alpha;
#pragma unroll
        for (int hf = 0; hf < 4; ++hf) oo[hf] *= alpha;
      }
#pragma unroll
      for (int j = 0; j < 4; ++j) {
        float p0 = exp2f(s[j][0] - mm), p1 = exp2f(s[j][1] - mm);
        float p2 = exp2f(s[j][2] - mm), p3 = exp2f(s[j][3] - mm);
        u32 lo = __builtin_bit_cast(u32, __builtin_amdgcn_cvt_pkrtz(p0, p1));
        u32 hi = __builtin_bit_cast(u32, __builtin_amdgcn_cvt_pkrtz(p2, p3));
        pb[j] = __builtin_bit_cast(f16x4, (u32x2){lo, hi});
      }
    };

    f16x4 pbA[4], pbB[4];
    softmax(sA, mA, oA, osA, pbA);
    if (actB) softmax(sB, mB, oB, osB, pbB);

    // ---- PV: V fragments read once, shared by both fragments ----
    __builtin_amdgcn_s_setprio(1);
#pragma unroll
    for (int j = 0; j < 4; ++j) {
      const int pc = (((2 * j + lgh) ^ rx) << 3) + lgb;  // f16 elems
#pragma unroll
      for (int hf = 0; hf < 4; ++hf) {
        f16x4 vf = *(const f16x4*)(&Vs[cur][hf * 16 + l15][0] + pc);
        oA[hf] = __builtin_amdgcn_mfma_f32_16x16x16f16(vf, pbA[j], oA[hf], 0, 0, 0);
        if (actB) oB[hf] = __builtin_amdgcn_mfma_f32_16x16x16f16(vf, pbB[j], oB[hf], 0, 0, 0);
      }
      osA = __builtin_amdgcn_mfma_f32_16x16x16f16(ones16, pbA[j], osA, 0, 0, 0);
      if (actB) osB = __builtin_amdgcn_mfma_f32_16x16x16f16(ones16, pbB[j], osB, 0, 0, 0);
    }
    __builtin_amdgcn_s_setprio(0);
  }

  // ---- epilogue: normalize + store both fragments ----
  {
    float inv = 1.0f / osA[0];
    u16* Orow = attnb + (size_t)(b * S_ + q0A + l15) * D_ + h * HD_ + lg * 4;
#pragma unroll
    for (int hf = 0; hf < 4; ++hf) {
      u16x4 ov = {f2bf(oA[hf][0] * inv), f2bf(oA[hf][1] * inv),
                  f2bf(oA[hf][2] * inv), f2bf(oA[hf][3] * inv)};
      *(u16x4*)(Orow + hf * 16) = ov;
    }
  }
  {
    float inv = 1.0f / osB[0];
    u16* Orow = attnb + (size_t)(b * S_ + q0B + l15) * D_ + h * HD_ + lg * 4;
#pragma unroll
    for (int hf = 0; hf < 4; ++hf) {
      u16x4 ov = {f2bf(oB[hf][0] * inv), f2bf(oB[hf][1] * inv),
                  f2bf(oB[hf][2] * inv), f2bf(oB[hf][3] * inv)};
      *(u16x4*)(Orow + hf * 16) = ov;
    }
  }
}

// ---------------- output projection GEMM (fp32 out + bias, XCD-clustered swizzle) ----------------
__global__ __launch_bounds__(256) void out_gemm_kernel(const u16* __restrict__ attnb, const u16* __restrict__ Wot,
                                                       const float* __restrict__ bo, float* __restrict__ outp) {
  __shared__ u16 As[128 * 64];
  __shared__ u16 Bs[128 * 64];
  int lin = blockIdx.x;
  int xcd = lin & 7, pos = lin >> 3;  // pos in [0,64)
  int by = xcd * 8 + (pos >> 3);
  int bx = pos & 7;
  f32x4 acc[4][4] = {};
  int row0 = by * 128, col0 = bx * 128;
  gemm_main(attnb, Wot, As, Bs, row0, col0, acc);
  int lane = threadIdx.x & 63, wave = threadIdx.x >> 6;
  int wr = wave >> 1, wc = wave & 1, l15 = lane & 15, lg = lane >> 4;
  int rbase = row0 + wr * 64 + lg * 4, cbase = col0 + wc * 64 + l15;
#pragma unroll
  for (int n = 0; n < 4; ++n) {
    float bn = bo[cbase + n * 16];
#pragma unroll
    for (int m = 0; m < 4; ++m)
#pragma unroll
      for (int r = 0; r < 4; ++r)
        outp[(size_t)(rbase + m * 16 + r) * D_ + cbase + n * 16] = acc[m][n][r] + bn;
  }
}

extern "C" void kernel_launch(void* const* d_in, const int* in_sizes, int n_in,
                              void* d_out, int out_size, void* d_ws, size_t ws_size,
                              hipStream_t stream) {
  const float* x  = (const float*)d_in[0];
  const float* Wq = (const float*)d_in[1];
  const float* Wk = (const float*)d_in[2];
  const float* Wv = (const float*)d_in[3];
  const float* Wo = (const float*)d_in[4];
  const float* bo = (const float*)d_in[5];
  float* outp = (float*)d_out;

  char* ws = (char*)d_ws;
  u16* xb        = (u16*)(ws);                          // 16 MiB
  u16* Wqt       = (u16*)(ws + ((size_t)16 << 20));     // 2 MiB
  u16* Wkt       = (u16*)(ws + ((size_t)18 << 20));
  u16* Wvt       = (u16*)(ws + ((size_t)20 << 20));
  u16* Wot       = (u16*)(ws + ((size_t)22 << 20));
  u16* Qb        = (u16*)(ws + ((size_t)24 << 20));     // 16 MiB
  u16* Kb        = (u16*)(ws + ((size_t)40 << 20));     // 16 MiB
  _Float16* Vt   = (_Float16*)(ws + ((size_t)56 << 20));// 16 MiB
  u16* attnb     = (u16*)(ws + ((size_t)72 << 20));     // 16 MiB

  cast_x_kernel<<<dim3(M_ * D_ / (256 * 4)), dim3(256), 0, stream>>>(x, xb);
  wtrans_kernel<<<dim3(16, 16, 4), dim3(256), 0, stream>>>(Wq, Wk, Wv, Wo, Wqt, Wkt, Wvt, Wot);
  qkv_gemm_kernel<<<dim3(1536), dim3(256), 0, stream>>>(xb, Wqt, Wkt, Wvt, Qb, Kb, Vt);
  attn_kernel<<<dim3(1024), dim3(256), 0, stream>>>(Qb, Kb, Vt, attnb);
  out_gemm_kernel<<<dim3(512), dim3(256), 0, stream>>>(attnb, Wot, bo, outp);
}